// Round 5
// baseline (29.779 us; speedup 1.0000x reference)
//
#include <hip/hip_runtime.h>
#include <math.h>

// Hausdorff distance, X[8192,3] vs Y[8192,3] fp32.
// d2(i,j) = |a_i|^2 - 2*max_term, max_term = max_j (a_i . b_j - |b_j|^2/2).
// Rows packed as float2 -> v_pk_fma_f32 (2.5 VALU instr per pair).
// 2 dispatches: pair_partial (1024 blocks, also zeroes out) ->
//               reduce_final (64 blocks, min over chunks, max, sqrt, atomicMax).

typedef float v2f __attribute__((ext_vector_type(2)));

constexpr int NPTS = 8192;
constexpr int T = 256;             // threads per block
constexpr int R = 4;               // rows per thread (2 float2 groups)
constexpr int ROWS_PB = T * R;     // 1024
constexpr int RG = NPTS / ROWS_PB; // 8 row groups
constexpr int CG = 64;             // col chunks per direction
constexpr int COLS = NPTS / CG;    // 128 B-points per block

__global__ __launch_bounds__(T) void pair_partial_kernel(
        const float* __restrict__ X, const float* __restrict__ Y,
        float* __restrict__ partial, float* __restrict__ out) {
    int b = blockIdx.x;
    if (b == 0 && threadIdx.x == 0) out[0] = 0.f;  // reset before reduce_final
    int dir = b / (RG * CG);
    int rem = b - dir * (RG * CG);
    int rg = rem / CG;
    int cg = rem - rg * CG;
    const float* A = dir ? Y : X;
    const float* B = dir ? X : Y;

    int t = threadIdx.x;
    int r0 = rg * ROWS_PB + t;

    // A rows -> registers (issue early; latency hides under staging)
    float ax[R], ay[R], az[R];
#pragma unroll
    for (int k = 0; k < R; ++k) {
        int row = r0 + k * T;
        ax[k] = A[row * 3 + 0];
        ay[k] = A[row * 3 + 1];
        az[k] = A[row * 3 + 2];
    }

    // Stage B chunk as (x, y, z, -0.5*|b|^2)
    __shared__ float4 Bs[COLS];
    for (int i = t; i < COLS; i += T) {
        int j = cg * COLS + i;
        float bx = B[j * 3 + 0], by = B[j * 3 + 1], bz = B[j * 3 + 2];
        Bs[i] = make_float4(bx, by, bz, -0.5f * fmaf(bx, bx, fmaf(by, by, bz * bz)));
    }

    v2f ax2[R / 2], ay2[R / 2], az2[R / 2], na2[R / 2], mt2[R / 2];
#pragma unroll
    for (int q = 0; q < R / 2; ++q) {
        ax2[q] = (v2f){ax[2 * q], ax[2 * q + 1]};
        ay2[q] = (v2f){ay[2 * q], ay[2 * q + 1]};
        az2[q] = (v2f){az[2 * q], az[2 * q + 1]};
        na2[q] = ax2[q] * ax2[q] + ay2[q] * ay2[q] + az2[q] * az2[q];
        mt2[q] = (v2f){-__builtin_inff(), -__builtin_inff()};
    }
    __syncthreads();

#pragma unroll 4
    for (int j = 0; j < COLS; ++j) {
        float4 p = Bs[j];  // wave-uniform -> ds_read_b128 broadcast, 0 conflicts
        v2f px = (v2f){p.x, p.x};
        v2f py = (v2f){p.y, p.y};
        v2f pz = (v2f){p.z, p.z};
        v2f pw = (v2f){p.w, p.w};
#pragma unroll
        for (int q = 0; q < R / 2; ++q) {
            v2f tt = az2[q] * pz + pw;   // fp-contract -> v_pk_fma_f32
            tt = ay2[q] * py + tt;
            tt = ax2[q] * px + tt;
            mt2[q].x = fmaxf(mt2[q].x, tt.x);
            mt2[q].y = fmaxf(mt2[q].y, tt.y);
        }
    }

    // partial d2-min for this col chunk; coalesced stores
    float* op = partial + (size_t)(dir * CG + cg) * NPTS + rg * ROWS_PB + t;
#pragma unroll
    for (int q = 0; q < R / 2; ++q) {
        op[(2 * q) * T]     = fmaf(-2.f, mt2[q].x, na2[q].x);
        op[(2 * q + 1) * T] = fmaf(-2.f, mt2[q].y, na2[q].y);
    }
}

__global__ __launch_bounds__(T) void reduce_final_kernel(
        const float* __restrict__ partial, float* __restrict__ out) {
    int rid = blockIdx.x * T + threadIdx.x;  // 0..16383
    int dir = rid >> 13;
    int row = rid & (NPTS - 1);
    const float* p = partial + (size_t)dir * CG * NPTS + row;

    // 64 independent strided loads, 8 accumulators -> deep VMEM pipelining
    float m[8];
#pragma unroll
    for (int k = 0; k < 8; ++k) m[k] = __builtin_inff();
#pragma unroll
    for (int cg = 0; cg < CG; ++cg)
        m[cg & 7] = fminf(m[cg & 7], p[(size_t)cg * NPTS]);
#pragma unroll
    for (int k = 0; k < 4; ++k) m[k] = fminf(m[k], m[k + 4]);
    float mm = fminf(fminf(m[0], m[1]), fminf(m[2], m[3]));
    float d = sqrtf(fmaxf(mm, 0.f));  // dot-form can dip slightly negative

    for (int o = 32; o > 0; o >>= 1) d = fmaxf(d, __shfl_down(d, o));
    __shared__ float wm[T / 64];
    if ((threadIdx.x & 63) == 0) wm[threadIdx.x >> 6] = d;
    __syncthreads();
    if (threadIdx.x == 0) {
        float bm = wm[0];
        for (int w = 1; w < T / 64; ++w) bm = fmaxf(bm, wm[w]);
        // non-negative float bits order like unsigned
        atomicMax((unsigned*)out, __float_as_uint(bm));
    }
}

// ---------- fallback path (small ws): atomic version ----------

constexpr int SEG_J = 512;
constexpr int SEGS = NPTS / SEG_J;

__global__ void init_min_kernel(unsigned* wsmin, int n) {
    int i = blockIdx.x * blockDim.x + threadIdx.x;
    if (i < n) wsmin[i] = 0x7F800000u;
}

__global__ __launch_bounds__(T) void pair_min_kernel(
        const float* __restrict__ X, const float* __restrict__ Y,
        unsigned* __restrict__ minXY, unsigned* __restrict__ minYX) {
    constexpr int RPB = T * 8;
    constexpr int BLOCKS_PER_DIR = (NPTS / RPB) * SEGS;
    int b = blockIdx.x;
    int dir = b / BLOCKS_PER_DIR;
    int rem = b - dir * BLOCKS_PER_DIR;
    int rg = rem / SEGS;
    int seg = rem - rg * SEGS;
    const float* A = dir ? Y : X;
    const float* B = dir ? X : Y;
    unsigned* omin = dir ? minYX : minXY;

    __shared__ float Bs[SEG_J * 3];
    int t = threadIdx.x;
    const float* Bseg = B + seg * SEG_J * 3;
    for (int i = t; i < SEG_J * 3; i += T) Bs[i] = Bseg[i];

    int r0 = rg * RPB + t;
    float ax[8], ay[8], az[8], m[8];
#pragma unroll
    for (int r = 0; r < 8; ++r) {
        int row = r0 + r * T;
        ax[r] = A[row * 3 + 0];
        ay[r] = A[row * 3 + 1];
        az[r] = A[row * 3 + 2];
        m[r] = __builtin_inff();
    }
    __syncthreads();

#pragma unroll 2
    for (int j = 0; j < SEG_J; ++j) {
        float bx = Bs[3 * j + 0], by = Bs[3 * j + 1], bz = Bs[3 * j + 2];
#pragma unroll
        for (int r = 0; r < 8; ++r) {
            float dx = ax[r] - bx, dy = ay[r] - by, dz = az[r] - bz;
            m[r] = fminf(m[r], fmaf(dx, dx, fmaf(dy, dy, dz * dz)));
        }
    }
#pragma unroll
    for (int r = 0; r < 8; ++r)
        atomicMin(&omin[r0 + r * T], __float_as_uint(m[r]));
}

__global__ __launch_bounds__(T) void finalize_min_kernel(
        const unsigned* __restrict__ wsmin, float* __restrict__ out, int n) {
    int t = threadIdx.x;
    float mx = 0.f;
    for (int i = t; i < n; i += T) mx = fmaxf(mx, __uint_as_float(wsmin[i]));
    for (int o = 32; o > 0; o >>= 1) mx = fmaxf(mx, __shfl_down(mx, o));
    __shared__ float wmax[T / 64];
    if ((t & 63) == 0) wmax[t >> 6] = mx;
    __syncthreads();
    if (t == 0) {
        float mm = wmax[0];
        for (int w = 1; w < T / 64; ++w) mm = fmaxf(mm, wmax[w]);
        out[0] = sqrtf(mm);
    }
}

extern "C" void kernel_launch(void* const* d_in, const int* in_sizes, int n_in,
                              void* d_out, int out_size, void* d_ws, size_t ws_size,
                              hipStream_t stream) {
    const float* X = (const float*)d_in[0];
    const float* Y = (const float*)d_in[1];
    float* out = (float*)d_out;

    const size_t need = (size_t)(2 * CG * NPTS) * sizeof(float);

    if (ws_size >= need) {
        float* partial = (float*)d_ws;
        pair_partial_kernel<<<2 * RG * CG, T, 0, stream>>>(X, Y, partial, out);
        reduce_final_kernel<<<2 * NPTS / T, T, 0, stream>>>(partial, out);
    } else if (ws_size >= 2 * NPTS * sizeof(unsigned)) {
        unsigned* wsmin = (unsigned*)d_ws;
        init_min_kernel<<<(2 * NPTS + T - 1) / T, T, 0, stream>>>(wsmin, 2 * NPTS);
        pair_min_kernel<<<2 * (NPTS / (T * 8)) * SEGS, T, 0, stream>>>(
            X, Y, wsmin, wsmin + NPTS);
        finalize_min_kernel<<<1, T, 0, stream>>>(wsmin, out, 2 * NPTS);
    }
}

// Round 6
// 25.858 us; speedup vs baseline: 1.1516x; 1.1516x over previous
//
#include <hip/hip_runtime.h>
#include <math.h>

// Hausdorff distance, X[8192,3] vs Y[8192,3] fp32.
// d2(i,j) = |a_i|^2 - 2*max_term, max_term = max_j (a_i . b_j - |b_j|^2/2).
// Rows packed as float2 -> v_pk_fma_f32 (2.5 VALU instr per pair).
// R=8 rows/thread so each broadcast ds_read_b128 feeds 8 rows of math
// (LDS pipe is per-CU @ ~12cy/b128 -> must amortize reads, not just vectorize).
// 3 dispatches: pair_partial (512 blocks) -> reduce (64 blocks) -> final.

typedef float v2f __attribute__((ext_vector_type(2)));

constexpr int NPTS = 8192;
constexpr int T = 256;             // threads per block
constexpr int R = 8;               // rows per thread (4 float2 groups)
constexpr int ROWS_PB = T * R;     // 2048
constexpr int RG = NPTS / ROWS_PB; // 4 row groups
constexpr int CG = 64;             // col chunks per direction
constexpr int COLS = NPTS / CG;    // 128 B-points per block

__global__ __launch_bounds__(T) void pair_partial_kernel(
        const float* __restrict__ X, const float* __restrict__ Y,
        float* __restrict__ partial) {
    int b = blockIdx.x;
    int dir = b / (RG * CG);
    int rem = b - dir * (RG * CG);
    int rg = rem / CG;
    int cg = rem - rg * CG;
    const float* A = dir ? Y : X;
    const float* B = dir ? X : Y;

    int t = threadIdx.x;
    int r0 = rg * ROWS_PB + t;

    // A rows -> registers (issue early; latency hides under staging)
    float ax[R], ay[R], az[R];
#pragma unroll
    for (int k = 0; k < R; ++k) {
        int row = r0 + k * T;
        ax[k] = A[row * 3 + 0];
        ay[k] = A[row * 3 + 1];
        az[k] = A[row * 3 + 2];
    }

    // Stage B chunk as (x, y, z, -0.5*|b|^2)
    __shared__ float4 Bs[COLS];
    for (int i = t; i < COLS; i += T) {
        int j = cg * COLS + i;
        float bx = B[j * 3 + 0], by = B[j * 3 + 1], bz = B[j * 3 + 2];
        Bs[i] = make_float4(bx, by, bz, -0.5f * fmaf(bx, bx, fmaf(by, by, bz * bz)));
    }

    v2f ax2[R / 2], ay2[R / 2], az2[R / 2], na2[R / 2], mt2[R / 2];
#pragma unroll
    for (int q = 0; q < R / 2; ++q) {
        ax2[q] = (v2f){ax[2 * q], ax[2 * q + 1]};
        ay2[q] = (v2f){ay[2 * q], ay[2 * q + 1]};
        az2[q] = (v2f){az[2 * q], az[2 * q + 1]};
        na2[q] = ax2[q] * ax2[q] + ay2[q] * ay2[q] + az2[q] * az2[q];
        mt2[q] = (v2f){-__builtin_inff(), -__builtin_inff()};
    }
    __syncthreads();

#pragma unroll 8
    for (int j = 0; j < COLS; ++j) {
        float4 p = Bs[j];  // wave-uniform -> ds_read_b128 broadcast, 0 conflicts
        v2f px = (v2f){p.x, p.x};
        v2f py = (v2f){p.y, p.y};
        v2f pz = (v2f){p.z, p.z};
        v2f pw = (v2f){p.w, p.w};
#pragma unroll
        for (int q = 0; q < R / 2; ++q) {
            v2f tt = az2[q] * pz + pw;   // fp-contract -> v_pk_fma_f32
            tt = ay2[q] * py + tt;
            tt = ax2[q] * px + tt;
            mt2[q].x = fmaxf(mt2[q].x, tt.x);
            mt2[q].y = fmaxf(mt2[q].y, tt.y);
        }
    }

    // partial d2-min for this col chunk; coalesced stores
    float* op = partial + (size_t)(dir * CG + cg) * NPTS + rg * ROWS_PB + t;
#pragma unroll
    for (int q = 0; q < R / 2; ++q) {
        op[(2 * q) * T]     = fmaf(-2.f, mt2[q].x, na2[q].x);
        op[(2 * q + 1) * T] = fmaf(-2.f, mt2[q].y, na2[q].y);
    }
}

template <int CGN>
__global__ __launch_bounds__(T) void reduce_kernel(
        const float* __restrict__ partial, float* __restrict__ blockmax) {
    int rid = blockIdx.x * T + threadIdx.x;  // 0..16383
    int dir = rid >> 13;
    int row = rid & (NPTS - 1);
    const float* p = partial + (size_t)dir * CGN * NPTS + row;
    // two independent accumulators -> deeper load pipelining
    float m0 = __builtin_inff(), m1 = __builtin_inff();
#pragma unroll 8
    for (int cg = 0; cg < CGN; cg += 2) {
        m0 = fminf(m0, p[(size_t)cg * NPTS]);
        m1 = fminf(m1, p[(size_t)(cg + 1) * NPTS]);
    }
    float m = fmaxf(fminf(m0, m1), 0.f);  // dot-form can dip slightly negative
    for (int o = 32; o > 0; o >>= 1) m = fmaxf(m, __shfl_down(m, o));
    __shared__ float wm[T / 64];
    if ((threadIdx.x & 63) == 0) wm[threadIdx.x >> 6] = m;
    __syncthreads();
    if (threadIdx.x == 0) {
        float mm = wm[0];
        for (int w = 1; w < T / 64; ++w) mm = fmaxf(mm, wm[w]);
        blockmax[blockIdx.x] = mm;
    }
}

__global__ void final_kernel(const float* __restrict__ blockmax,
                             float* __restrict__ out, int n) {
    float m = blockmax[threadIdx.x < n ? threadIdx.x : 0];
    for (int o = 32; o > 0; o >>= 1) m = fmaxf(m, __shfl_down(m, o));
    if (threadIdx.x == 0) out[0] = sqrtf(m);
}

// ---------- fallback path (small ws): atomic version ----------

constexpr int SEG_J = 512;
constexpr int SEGS = NPTS / SEG_J;

__global__ void init_min_kernel(unsigned* wsmin, int n) {
    int i = blockIdx.x * blockDim.x + threadIdx.x;
    if (i < n) wsmin[i] = 0x7F800000u;
}

__global__ __launch_bounds__(T) void pair_min_kernel(
        const float* __restrict__ X, const float* __restrict__ Y,
        unsigned* __restrict__ minXY, unsigned* __restrict__ minYX) {
    constexpr int RPB = T * 8;
    constexpr int BLOCKS_PER_DIR = (NPTS / RPB) * SEGS;
    int b = blockIdx.x;
    int dir = b / BLOCKS_PER_DIR;
    int rem = b - dir * BLOCKS_PER_DIR;
    int rg = rem / SEGS;
    int seg = rem - rg * SEGS;
    const float* A = dir ? Y : X;
    const float* B = dir ? X : Y;
    unsigned* omin = dir ? minYX : minXY;

    __shared__ float Bs[SEG_J * 3];
    int t = threadIdx.x;
    const float* Bseg = B + seg * SEG_J * 3;
    for (int i = t; i < SEG_J * 3; i += T) Bs[i] = Bseg[i];

    int r0 = rg * RPB + t;
    float ax[8], ay[8], az[8], m[8];
#pragma unroll
    for (int r = 0; r < 8; ++r) {
        int row = r0 + r * T;
        ax[r] = A[row * 3 + 0];
        ay[r] = A[row * 3 + 1];
        az[r] = A[row * 3 + 2];
        m[r] = __builtin_inff();
    }
    __syncthreads();

#pragma unroll 2
    for (int j = 0; j < SEG_J; ++j) {
        float bx = Bs[3 * j + 0], by = Bs[3 * j + 1], bz = Bs[3 * j + 2];
#pragma unroll
        for (int r = 0; r < 8; ++r) {
            float dx = ax[r] - bx, dy = ay[r] - by, dz = az[r] - bz;
            m[r] = fminf(m[r], fmaf(dx, dx, fmaf(dy, dy, dz * dz)));
        }
    }
#pragma unroll
    for (int r = 0; r < 8; ++r)
        atomicMin(&omin[r0 + r * T], __float_as_uint(m[r]));
}

__global__ __launch_bounds__(T) void finalize_min_kernel(
        const unsigned* __restrict__ wsmin, float* __restrict__ out, int n) {
    int t = threadIdx.x;
    float mx = 0.f;
    for (int i = t; i < n; i += T) mx = fmaxf(mx, __uint_as_float(wsmin[i]));
    for (int o = 32; o > 0; o >>= 1) mx = fmaxf(mx, __shfl_down(mx, o));
    __shared__ float wmax[T / 64];
    if ((t & 63) == 0) wmax[t >> 6] = mx;
    __syncthreads();
    if (t == 0) {
        float mm = wmax[0];
        for (int w = 1; w < T / 64; ++w) mm = fmaxf(mm, wmax[w]);
        out[0] = sqrtf(mm);
    }
}

extern "C" void kernel_launch(void* const* d_in, const int* in_sizes, int n_in,
                              void* d_out, int out_size, void* d_ws, size_t ws_size,
                              hipStream_t stream) {
    const float* X = (const float*)d_in[0];
    const float* Y = (const float*)d_in[1];
    float* out = (float*)d_out;

    const size_t need = (size_t)(2 * CG * NPTS + 2 * NPTS / T) * sizeof(float);

    if (ws_size >= need) {
        float* partial = (float*)d_ws;
        float* blockmax = partial + 2 * CG * NPTS;
        pair_partial_kernel<<<2 * RG * CG, T, 0, stream>>>(X, Y, partial);
        reduce_kernel<CG><<<2 * NPTS / T, T, 0, stream>>>(partial, blockmax);
        final_kernel<<<1, 64, 0, stream>>>(blockmax, out, 2 * NPTS / T);
    } else if (ws_size >= 2 * NPTS * sizeof(unsigned)) {
        unsigned* wsmin = (unsigned*)d_ws;
        init_min_kernel<<<(2 * NPTS + T - 1) / T, T, 0, stream>>>(wsmin, 2 * NPTS);
        pair_min_kernel<<<2 * (NPTS / (T * 8)) * SEGS, T, 0, stream>>>(
            X, Y, wsmin, wsmin + NPTS);
        finalize_min_kernel<<<1, T, 0, stream>>>(wsmin, out, 2 * NPTS);
    }
}